// Round 6
// baseline (96.318 us; speedup 1.0000x reference)
//
#include <hip/hip_runtime.h>
#include <hip/hip_bf16.h>

#define B 32
#define C 512
#define HW 3136            // 56*56
#define HW4 784            // float4 columns per plane
#define TH 0.01f
#define CPB 16             // channels per block (kernel A)
#define CPW 4              // channels per wave
#define NPG 32             // partial groups = C/CPB

typedef float fx4 __attribute__((ext_vector_type(4)));

// ---------------------------------------------------------------------------
// Kernel A: single-pass partial saliency.
// Block = (b, cg) of 4 waves; each wave owns 4 channels. Per channel:
// lanes load the whole plane into regs (12-13 fx4/lane, nontemporal),
// tree-sum + in-wave shfl reduce -> alpha, then FMA the SAME regs into acc.
// x read from HBM exactly once. Partial written into d_out plane co=cg.
// ---------------------------------------------------------------------------
__global__ __launch_bounds__(256, 4) void partial_kernel(const float* __restrict__ x,
                                                         float* __restrict__ out) {
    const int b  = blockIdx.y;
    const int cg = blockIdx.x;          // 0..NPG-1
    const int t  = threadIdx.x;
    const int l  = t & 63;
    const int w  = t >> 6;

    const fx4* __restrict__ xb = (const fx4*)(x + (size_t)b * C * HW);

    fx4 acc[13];
    #pragma unroll
    for (int j = 0; j < 13; ++j) acc[j] = (fx4)0.f;

    const int cbase = cg * CPB + w * CPW;
    for (int i = 0; i < CPW; ++i) {
        const fx4* __restrict__ p = xb + (size_t)(cbase + i) * HW4;
        fx4 v[13];
        #pragma unroll
        for (int j = 0; j < 12; ++j) v[j] = __builtin_nontemporal_load(p + l + 64 * j);
        if (l < 16) v[12] = __builtin_nontemporal_load(p + l + 768);

        // tree-sum: 12 independent per-fx4 sums, then 4-level tree
        float ps[12];
        #pragma unroll
        for (int j = 0; j < 12; ++j) ps[j] = (v[j].x + v[j].y) + (v[j].z + v[j].w);
        float s12 = 0.f;
        if (l < 16) s12 = (v[12].x + v[12].y) + (v[12].z + v[12].w);
        const float q0 = (ps[0] + ps[1]) + (ps[2] + ps[3]);
        const float q1 = (ps[4] + ps[5]) + (ps[6] + ps[7]);
        const float q2 = (ps[8] + ps[9]) + (ps[10] + ps[11]);
        float s = (q0 + q1) + (q2 + s12);

        #pragma unroll
        for (int off = 1; off < 64; off <<= 1) s += __shfl_xor(s, off);
        const float a = s * (1.0f / (float)HW);   // alpha[b,c]

        #pragma unroll
        for (int j = 0; j < 12; ++j) acc[j] += v[j] * a;
        if (l < 16) acc[12] += v[12] * a;
    }

    // cross-wave reduce: waves 1..3 dump acc to LDS, wave 0 sums and writes.
    __shared__ fx4 lds[3][HW4];        // 37,632 B
    if (w > 0) {
        #pragma unroll
        for (int j = 0; j < 12; ++j) lds[w - 1][l + 64 * j] = acc[j];
        if (l < 16) lds[w - 1][l + 768] = acc[12];
    }
    __syncthreads();
    if (w == 0) {
        fx4* __restrict__ dst = (fx4*)(out + (size_t)b * C * HW) + (size_t)cg * HW4;
        #pragma unroll
        for (int j = 0; j < 12; ++j) {
            const int col = l + 64 * j;
            dst[col] = ((acc[j] + lds[0][col]) + (lds[1][col] + lds[2][col]));
        }
        if (l < 16) {
            const int col = l + 768;
            dst[col] = ((acc[12] + lds[0][col]) + (lds[1][col] + lds[2][col]));
        }
    }
}

// ---------------------------------------------------------------------------
// Kernel A2: sal[b][col] = (1/C) * sum over 32 partials (L2/L3-hot).
// sal lives in d_ws (32*784 fx4 = 401 KB, L2-resident for kernel B).
// ---------------------------------------------------------------------------
__global__ __launch_bounds__(256) void sal_reduce_kernel(const float* __restrict__ out,
                                                         fx4* __restrict__ sal) {
    const int b   = blockIdx.y;
    const int col = blockIdx.x * 256 + threadIdx.x;
    if (col >= HW4) return;
    const fx4* __restrict__ P = (const fx4*)(out + (size_t)b * C * HW) + col;
    fx4 s = (fx4)0.f;
    #pragma unroll
    for (int pg = 0; pg < NPG; ++pg) s += P[(size_t)pg * HW4];
    sal[b * HW4 + col] = s * (1.0f / (float)C);
}

// ---------------------------------------------------------------------------
// Kernel B: expansion with fully-contiguous NT stores.
// out[b] treated as flat 512*784 fx4. Block = (b, 1/49th of that range):
// 8192 fx4 = 32 iters x 256 threads; each wave stores 1 KB contiguous.
// sal[b] (12.5 KB) + w (2 KB) staged in LDS; col/co tracked incrementally.
// ---------------------------------------------------------------------------
__global__ __launch_bounds__(256) void out_kernel(const fx4* __restrict__ sal,
                                                  const float* __restrict__ w,
                                                  const float* __restrict__ scale_p,
                                                  const float* __restrict__ wf_p,
                                                  float* __restrict__ out) {
    const int b  = blockIdx.y;
    const int t  = threadIdx.x;
    const int F0 = blockIdx.x * 8192;          // flat fx4 offset within out[b]

    __shared__ fx4  sal_sm[HW4];               // 12,544 B
    __shared__ float w_sm[C];                  //  2,048 B
    const fx4* __restrict__ sb = sal + b * HW4;
    for (int i = t; i < HW4; i += 256) sal_sm[i] = sb[i];
    for (int i = t; i < C;   i += 256) w_sm[i]  = w[i];
    __syncthreads();

    const float scale = scale_p[0];
    const float wf    = wf_p[0];
    const float out_zero = 1.0f - 0.5f * wf;   // fm == 0 path

    fx4* __restrict__ ob = (fx4*)(out + (size_t)b * C * HW) + F0;

    int colb = F0 % HW4;                       // uniform per block
    int cob  = F0 / HW4;

    for (int it = 0; it < 32; ++it) {
        int c = colb + t;                      // < 784 + 256: wraps at most once
        const int wrapped = (c >= HW4) ? 1 : 0;
        c -= wrapped ? HW4 : 0;
        const int co = cob + wrapped;

        const fx4  s4 = sal_sm[c];
        const float wc = w_sm[co];

        fx4 r;
        float fm;
        fm = s4.x * wc;
        r.x = (fm > TH) ? 1.0f - wf / (1.0f + __expf(-scale * fm)) : out_zero;
        fm = s4.y * wc;
        r.y = (fm > TH) ? 1.0f - wf / (1.0f + __expf(-scale * fm)) : out_zero;
        fm = s4.z * wc;
        r.z = (fm > TH) ? 1.0f - wf / (1.0f + __expf(-scale * fm)) : out_zero;
        fm = s4.w * wc;
        r.w = (fm > TH) ? 1.0f - wf / (1.0f + __expf(-scale * fm)) : out_zero;
        __builtin_nontemporal_store(r, ob + it * 256 + t);

        colb += 256;
        if (colb >= HW4) { colb -= HW4; cob += 1; }
    }
}

extern "C" void kernel_launch(void* const* d_in, const int* in_sizes, int n_in,
                              void* d_out, int out_size, void* d_ws, size_t ws_size,
                              hipStream_t stream) {
    const float* x      = (const float*)d_in[0];
    const float* conv_w = (const float*)d_in[1];   // 512 floats
    const float* scale  = (const float*)d_in[2];
    const float* wf     = (const float*)d_in[3];
    float* out = (float*)d_out;
    fx4*   sal = (fx4*)d_ws;                       // 32*784 fx4 = 401 KB

    dim3 gridA(NPG, B);                            // 32 x 32 = 1024 blocks
    partial_kernel<<<gridA, 256, 0, stream>>>(x, out);

    dim3 gridA2((HW4 + 255) / 256, B);             // 4 x 32
    sal_reduce_kernel<<<gridA2, 256, 0, stream>>>(out, sal);

    dim3 gridB(49, B);                             // 49 x 32 = 1568 blocks
    out_kernel<<<gridB, 256, 0, stream>>>(sal, conv_w, scale, wf, out);
}